// Round 1
// baseline (234.869 us; speedup 1.0000x reference)
//
#include <hip/hip_runtime.h>
#include <hip/hip_bf16.h>

typedef unsigned short u16;
typedef unsigned int u32;
typedef __attribute__((ext_vector_type(8))) short short8;
typedef __attribute__((ext_vector_type(4))) float f32x4;

#define NN 8192
#define FIN 512
#define FOUT 128
#define NEG 0.2f

__device__ __forceinline__ u16 f2bf(float f) {
  u32 u = __builtin_bit_cast(u32, f);
  u32 r = (u + 0x7fffu + ((u >> 16) & 1u)) >> 16;
  return (u16)r;
}

// K1: h = x @ w  (fp32), also emit Hb = bf16(h) in blocked-transposed-swizzled
// layout: Hb[chunk c][col n][jj ^ ((n&7)<<3)] with c=row/128, jj=row%128.
__global__ __launch_bounds__(256) void k_h(const float* __restrict__ x,
                                           const float* __restrict__ w,
                                           float* __restrict__ h,
                                           u16* __restrict__ hb) {
  __shared__ float xs[32][68];     // +4 pad: breaks 8-way bank conflict on xs[r][kk]
  __shared__ float ws_[64][128];
  const int t = threadIdx.x;
  const int r0 = blockIdx.x * 32;
  const int r = t >> 3;            // 0..31, 8 threads per row
  const int cq = (t & 7) * 4;      // col groups: cq + 32*g + e (conflict-free float4 reads)
  float acc[4][4] = {};
  for (int kc = 0; kc < FIN; kc += 64) {
    __syncthreads();
    {
      const int rr = t >> 3, cc = (t & 7) * 8;
      const float4* src = (const float4*)(x + (size_t)(r0 + rr) * FIN + kc + cc);
      *(float4*)&xs[rr][cc] = src[0];
      *(float4*)&xs[rr][cc + 4] = src[1];
    }
#pragma unroll
    for (int i = 0; i < 8; ++i) {
      const int off = i * 1024 + t * 4;
      const int wr = off >> 7, wc = off & 127;
      *(float4*)&ws_[wr][wc] = *(const float4*)(w + (size_t)(kc + wr) * FOUT + wc);
    }
    __syncthreads();
    for (int kk = 0; kk < 64; ++kk) {
      const float xv = xs[r][kk];
#pragma unroll
      for (int g = 0; g < 4; ++g) {
        const float4 wv = *(const float4*)&ws_[kk][cq + 32 * g];
        acc[g][0] = fmaf(xv, wv.x, acc[g][0]);
        acc[g][1] = fmaf(xv, wv.y, acc[g][1]);
        acc[g][2] = fmaf(xv, wv.z, acc[g][2]);
        acc[g][3] = fmaf(xv, wv.w, acc[g][3]);
      }
    }
  }
  const int rg = r0 + r;
  const int ch = rg >> 7;
  const int jj = rg & 127;
#pragma unroll
  for (int g = 0; g < 4; ++g) {
    float4 v;
    v.x = acc[g][0]; v.y = acc[g][1]; v.z = acc[g][2]; v.w = acc[g][3];
    *(float4*)(h + (size_t)rg * FOUT + cq + 32 * g) = v;
#pragma unroll
    for (int e = 0; e < 4; ++e) {
      const int n = cq + 32 * g + e;
      hb[(size_t)ch * 16384 + n * 128 + (jj ^ ((n & 7) << 3))] = f2bf(acc[g][e]);
    }
  }
}

// K2: s = h @ a[:128], t = h @ a[128:].  One wave per row.
__global__ __launch_bounds__(256) void k_scores(const float* __restrict__ h,
                                                const float* __restrict__ a,
                                                float* __restrict__ s,
                                                float* __restrict__ t) {
  const int wid = threadIdx.x >> 6, lane = threadIdx.x & 63;
  const int row = blockIdx.x * 4 + wid;
  const float2 hv = *(const float2*)(h + (size_t)row * FOUT + lane * 2);
  const float2 a0 = *(const float2*)(a + lane * 2);
  const float2 a1 = *(const float2*)(a + FOUT + lane * 2);
  float ps = hv.x * a0.x + hv.y * a0.y;
  float pt = hv.x * a1.x + hv.y * a1.y;
#pragma unroll
  for (int d = 1; d < 64; d <<= 1) {
    ps += __shfl_xor(ps, d);
    pt += __shfl_xor(pt, d);
  }
  if (lane == 0) { s[row] = ps; t[row] = pt; }
}

// K3: tmax = max(t)
__global__ __launch_bounds__(256) void k_tmax(const float* __restrict__ t,
                                              float* __restrict__ tmax) {
  __shared__ float red[256];
  float m = -1e30f;
  for (int i = threadIdx.x; i < NN; i += 256) m = fmaxf(m, t[i]);
  red[threadIdx.x] = m;
  __syncthreads();
  for (int s2 = 128; s2 > 0; s2 >>= 1) {
    if (threadIdx.x < s2) red[threadIdx.x] = fmaxf(red[threadIdx.x], red[threadIdx.x + s2]);
    __syncthreads();
  }
  if (threadIdx.x == 0) tmax[0] = red[0];
}

// K4: per 16-row block: pass A streams adj once (bitmask->LDS, denom l_i with
// safe upper-bound max m_i = lrelu(s_i + tmax)); pass B writes normalized fp32
// attention and accumulates h' = attn @ h via bf16 MFMA.
__global__ __launch_bounds__(512) void k_attn(const int* __restrict__ adj,
                                              const float* __restrict__ sg,
                                              const float* __restrict__ tg,
                                              const float* __restrict__ tmaxp,
                                              const u16* __restrict__ hb,
                                              float* __restrict__ att,
                                              float* __restrict__ hp) {
  __shared__ u32 mask[16 * 256];   // 16 KB: adj bits for the block's 16 rows
  __shared__ float ts[NN];         // 32 KB: full t vector
  __shared__ u16 pl[16 * 128];     // 4 KB: bf16 P tile, XOR-swizzled rows
  __shared__ float s_s[16], s_m[16], s_l[16], s_inv[16];
  const int tid = threadIdx.x;
  const int w = tid >> 6, lane = tid & 63;
  const int r0 = blockIdx.x << 4;

  for (int i = tid * 4; i < NN; i += 2048)
    *(float4*)&ts[i] = *(const float4*)(tg + i);
  if (tid < 16) {
    const float sv = sg[r0 + tid];
    const float v = sv + tmaxp[0];
    s_s[tid] = sv;
    s_m[tid] = fmaxf(v, NEG * v);   // lrelu(s_i + tmax) >= all row entries (monotone)
  }
  __syncthreads();

  const int rA = 2 * w, rB = rA + 1;  // each wave owns 2 rows
  const float sA = s_s[rA], mA = s_m[rA];
  const float sB = s_s[rB], mB = s_m[rB];
  float sum0 = 0.f, sum1 = 0.f;
  {
    const int4* adjA = (const int4*)(adj + (size_t)(r0 + rA) * NN);
    const int4* adjB = (const int4*)(adj + (size_t)(r0 + rB) * NN);
#pragma unroll 4
    for (int it = 0; it < 32; ++it) {
      const int jb = it * 256;
      const int4 a0 = adjA[it * 64 + lane];
      const int4 a1 = adjB[it * 64 + lane];
      const float4 tv = *(const float4*)&ts[jb + lane * 4];
      u32 nib0 = 0u, nib1 = 0u;
      {
        float e, p, sm = 0.f;
        e = sA + tv.x; e = fmaxf(e, NEG * e); p = __expf(e - mA); sm += (a0.x > 0) ? p : 0.f; nib0 |= (a0.x > 0) ? 1u : 0u;
        e = sA + tv.y; e = fmaxf(e, NEG * e); p = __expf(e - mA); sm += (a0.y > 0) ? p : 0.f; nib0 |= (a0.y > 0) ? 2u : 0u;
        e = sA + tv.z; e = fmaxf(e, NEG * e); p = __expf(e - mA); sm += (a0.z > 0) ? p : 0.f; nib0 |= (a0.z > 0) ? 4u : 0u;
        e = sA + tv.w; e = fmaxf(e, NEG * e); p = __expf(e - mA); sm += (a0.w > 0) ? p : 0.f; nib0 |= (a0.w > 0) ? 8u : 0u;
        sum0 += sm;
      }
      {
        float e, p, sm = 0.f;
        e = sB + tv.x; e = fmaxf(e, NEG * e); p = __expf(e - mB); sm += (a1.x > 0) ? p : 0.f; nib1 |= (a1.x > 0) ? 1u : 0u;
        e = sB + tv.y; e = fmaxf(e, NEG * e); p = __expf(e - mB); sm += (a1.y > 0) ? p : 0.f; nib1 |= (a1.y > 0) ? 2u : 0u;
        e = sB + tv.z; e = fmaxf(e, NEG * e); p = __expf(e - mB); sm += (a1.z > 0) ? p : 0.f; nib1 |= (a1.z > 0) ? 4u : 0u;
        e = sB + tv.w; e = fmaxf(e, NEG * e); p = __expf(e - mB); sm += (a1.w > 0) ? p : 0.f; nib1 |= (a1.w > 0) ? 8u : 0u;
        sum1 += sm;
      }
      // pack 64 lanes * 4 bits -> u32 words (lanes 0 mod 8 hold lanes l..l+7)
      u32 v0 = nib0;
      v0 |= __shfl_xor(v0, 1) << 4;
      v0 |= __shfl_xor(v0, 2) << 8;
      v0 |= __shfl_xor(v0, 4) << 16;
      u32 v1 = nib1;
      v1 |= __shfl_xor(v1, 1) << 4;
      v1 |= __shfl_xor(v1, 2) << 8;
      v1 |= __shfl_xor(v1, 4) << 16;
      if ((lane & 7) == 0) {
        mask[rA * 256 + (jb >> 5) + (lane >> 3)] = v0;
        mask[rB * 256 + (jb >> 5) + (lane >> 3)] = v1;
      }
    }
  }
#pragma unroll
  for (int d = 1; d < 64; d <<= 1) {
    sum0 += __shfl_xor(sum0, d);
    sum1 += __shfl_xor(sum1, d);
  }
  if (lane == 0) { s_l[rA] = sum0; s_l[rB] = sum1; }
  __syncthreads();
  if (tid < 16) s_inv[tid] = 1.0f / s_l[tid];
  __syncthreads();

  const float invA = s_inv[rA], invB = s_inv[rB];
  const int bcol = 16 * w + (lane & 15);  // this wave's 16 output cols
  const int kg = lane >> 4;
  const int arow = lane & 15;
  f32x4 acc = {0.f, 0.f, 0.f, 0.f};
  float* attA = att + (size_t)(r0 + rA) * NN;
  float* attB = att + (size_t)(r0 + rB) * NN;

  for (int ck = 0; ck < 64; ++ck) {
    const int j0 = ck << 7;
    {
      const float2 tv = *(const float2*)&ts[j0 + 2 * lane];
      const int wi = ck * 4 + (lane >> 4);
      const int sh0 = (2 * lane) & 31;
      {
        const u32 wd = mask[rA * 256 + wi];
        const u32 b0 = (wd >> sh0) & 1u, b1 = (wd >> (sh0 + 1)) & 1u;
        float e0 = sA + tv.x; e0 = fmaxf(e0, NEG * e0);
        float e1 = sA + tv.y; e1 = fmaxf(e1, NEG * e1);
        const float p0 = b0 ? __expf(e0 - mA) * invA : 0.f;
        const float p1 = b1 ? __expf(e1 - mA) * invA : 0.f;
        float2 o; o.x = p0; o.y = p1;
        *(float2*)(attA + j0 + 2 * lane) = o;
        const u32 pk = (u32)f2bf(p0) | ((u32)f2bf(p1) << 16);
        *(u32*)&pl[rA * 128 + ((2 * lane) ^ ((rA & 7) << 3))] = pk;
      }
      {
        const u32 wd = mask[rB * 256 + wi];
        const u32 b0 = (wd >> sh0) & 1u, b1 = (wd >> (sh0 + 1)) & 1u;
        float e0 = sB + tv.x; e0 = fmaxf(e0, NEG * e0);
        float e1 = sB + tv.y; e1 = fmaxf(e1, NEG * e1);
        const float p0 = b0 ? __expf(e0 - mB) * invB : 0.f;
        const float p1 = b1 ? __expf(e1 - mB) * invB : 0.f;
        float2 o; o.x = p0; o.y = p1;
        *(float2*)(attB + j0 + 2 * lane) = o;
        const u32 pk = (u32)f2bf(p0) | ((u32)f2bf(p1) << 16);
        *(u32*)&pl[rB * 128 + ((2 * lane) ^ ((rB & 7) << 3))] = pk;
      }
    }
    __syncthreads();
    {
      const u16* hc = hb + (size_t)ck * 16384 + (size_t)bcol * 128;
#pragma unroll
      for (int ks = 0; ks < 4; ++ks) {
        const int ko = ks * 32 + kg * 8;
        const short8 bf = *(const short8*)(hc + (ko ^ ((bcol & 7) << 3)));
        const short8 af = *(const short8*)&pl[arow * 128 + (ko ^ ((arow & 7) << 3))];
        acc = __builtin_amdgcn_mfma_f32_16x16x32_bf16(af, bf, acc, 0, 0, 0);
      }
    }
    __syncthreads();
  }
#pragma unroll
  for (int q = 0; q < 4; ++q) {
    const int rr = kg * 4 + q;  // C/D: col=lane&15, row=(lane>>4)*4+reg
    hp[(size_t)(r0 + rr) * FOUT + bcol] = acc[q];
  }
}

extern "C" void kernel_launch(void* const* d_in, const int* in_sizes, int n_in,
                              void* d_out, int out_size, void* d_ws, size_t ws_size,
                              hipStream_t stream) {
  const float* x = (const float*)d_in[0];
  const int* adj = (const int*)d_in[1];
  const float* w = (const float*)d_in[2];
  const float* a = (const float*)d_in[3];
  float* out = (float*)d_out;
  float* att = out;
  float* hp = out + (size_t)NN * NN;  // h' slot
  float* h = hp;                      // fp32 h scratch lives in h' slot (K4 overwrites at end)
  u16* hb = (u16*)d_ws;               // 2 MB blocked-transposed bf16 h
  float* s = (float*)((char*)d_ws + (size_t)NN * FOUT * sizeof(u16));
  float* t = s + NN;
  float* tmax = t + NN;

  k_h<<<256, 256, 0, stream>>>(x, w, h, hb);
  k_scores<<<2048, 256, 0, stream>>>(h, a, s, t);
  k_tmax<<<1, 256, 0, stream>>>(t, tmax);
  k_attn<<<512, 512, 0, stream>>>(adj, s, t, tmax, hb, att, hp);
}